// Round 15
// baseline (278.088 us; speedup 1.0000x reference)
//
#include <hip/hip_runtime.h>

typedef unsigned short u16;
typedef __attribute__((ext_vector_type(8))) short bf16x8;
typedef __attribute__((ext_vector_type(4))) float f32x4;
typedef __attribute__((ext_vector_type(4))) u16 u16x4;

#define MFMA16(a, b, c) __builtin_amdgcn_mfma_f32_16x16x32_bf16(a, b, c, 0, 0, 0)

__device__ __forceinline__ u16 f2bf(float f) {
    union { float f; unsigned u; } v; v.f = f;
    unsigned r = (v.u + 0x7FFFu + ((v.u >> 16) & 1u)) >> 16;  // RNE
    return (u16)r;
}

__device__ __forceinline__ void gload_lds16(const void* g, void* l) {
    __builtin_amdgcn_global_load_lds((const __attribute__((address_space(1))) void*)g,
                                     (__attribute__((address_space(3))) void*)l, 16, 0, 0);
}

// ---------- prep: fp32 -> bf16 (optionally scaled) ----------
__global__ __launch_bounds__(256) void cvt_kernel(const float* __restrict__ src,
                                                  u16* __restrict__ dst, int n4, float scale) {
    int i = blockIdx.x * 256 + threadIdx.x;
    if (i >= n4) return;
    f32x4 v = *(const f32x4*)(src + (size_t)i * 4);
    u16x4 o;
#pragma unroll
    for (int j = 0; j < 4; ++j) o[j] = f2bf(v[j] * scale);
    *(u16x4*)(dst + (size_t)i * 4) = o;
}

// ---------- prep: V (8192x512 f32) -> Vt (512x8192 bf16) ----------
__global__ __launch_bounds__(256) void prep_vt(const float* __restrict__ V, u16* __restrict__ Vt) {
    __shared__ float tile[64][65];
    int t = threadIdx.x;
    int n0 = blockIdx.x * 64;
    int d0 = blockIdx.y * 64;
    int tr = t >> 4, tc = t & 15;
#pragma unroll
    for (int p = 0; p < 4; ++p) {
        int n = p * 16 + tr;
        f32x4 v = *(const f32x4*)(V + (size_t)(n0 + n) * 512 + d0 + tc * 4);
#pragma unroll
        for (int j = 0; j < 4; ++j) tile[n][tc * 4 + j] = v[j];
    }
    __syncthreads();
#pragma unroll
    for (int p = 0; p < 4; ++p) {
        int d = p * 16 + tr;
        u16x4 o;
#pragma unroll
        for (int j = 0; j < 4; ++j) o[j] = f2bf(tile[tc * 4 + j][d]);
        *(u16x4*)(Vt + (size_t)(d0 + d) * 8192 + n0 + tc * 4) = o;
    }
}

// ---------- flash attention: BM=64, KVBLK=64, key-split 2, kh-split S-phase ----------
// 8 waves = rs(2 x 32 Q-rows) x nj(2 x 32 keys) x kh(2 x 256 K-halves).
// Each wave: 32x32 S-partial over its K-half; each A-frag read feeds 2 MFMAs (2 row-tiles)
// -> S-phase LDS reads halved vs 16-row waves. Partner (wid^1) partial-exchange via lds_sx;
// each wave exps its owned 16-row half. Single P buffer, PV at iter end.
__global__ __launch_bounds__(512) void flash_kernel(
    const u16* __restrict__ Qs, const u16* __restrict__ Kb, const u16* __restrict__ Vt,
    float* __restrict__ Opart, float* __restrict__ lpart) {
    __shared__ __align__(16) u16 lds_k[2][64 * 512];  // 128 KB dbuf, 16B-chunk XOR swizzle
    __shared__ __align__(16) u16 lds_p[64 * 64];      // 8 KB P tile, swizzled
    __shared__ __align__(16) float lds_sx[16 * 256];  // 16 KB partial exchange
    __shared__ float s_l[2][64];

    const int tid = threadIdx.x;
    const int wid = tid >> 6;
    const int lane = tid & 63;
    const int lo = lane & 15;
    const int hi = lane >> 4;
    const int kh = wid & 1;         // K-half (2 x 256)
    const int nj = (wid >> 1) & 1;  // key half (2 x 32)
    const int rs = wid >> 2;        // row strip (2 x 32)

    // same-XCD blocks share a key-split (L2 reuse of the K/V stream)
    const int bx = blockIdx.x;
    const int x = bx & 7;
    const int g = bx >> 3;
    const int ks = x >> 2;
    const int mtile = g * 4 + (x & 3);
    const int key0 = ks * 4096;

    // Q fragments (B-operand of swapped S-MFMA): 2 row-tiles x 8 kt over this K-half. 64 VGPR.
    bf16x8 qf[2][8];
#pragma unroll
    for (int rt = 0; rt < 2; ++rt) {
        const u16* qrow =
            Qs + (size_t)(mtile * 64 + rs * 32 + rt * 16 + lo) * 512 + kh * 256 + hi * 8;
#pragma unroll
        for (int j = 0; j < 8; ++j) qf[rt][j] = *(const bf16x8*)(qrow + j * 32);
    }

    f32x4 o[4][4];
#pragma unroll
    for (int a = 0; a < 4; ++a)
#pragma unroll
        for (int b = 0; b < 4; ++b) o[a][b] = (f32x4){0.f, 0.f, 0.f, 0.f};
    float lsum = 0.f;
    bf16x8 vb[4][2];

    // S-read addressing (R10-verified): chunk(kt) = (kh*32 + kt*4 + hi) ^ (krow&7),
    // krow = nj*32 (+16 for at=1) + lo; kh*32 is bit5 -> unaffected by the XOR.
    const int cbase = ((hi ^ (lo & 3)) + ((lo >> 2) & 1) * 4) * 8;
    const int rowA = (nj * 32 + lo) * 512;
    const int khofs = kh * 256;

    // P-write (R10-verified form): row = rs*32 + kh*16 + lo (this wave's owned rows);
    // keys nj*32 + at*16 + hi*4 + r -> chunk16 (nj*4 + at*2 + (hi>>1)) ^ (row&7)
    const int prow = rs * 32 + kh * 16 + lo;
    const int pw0 = prow * 64 + ((((nj << 2) + (hi >> 1)) ^ (prow & 7)) << 3) + (hi & 1) * 4;
    const int pw1 = prow * 64 + ((((nj << 2) + 2 + (hi >> 1)) ^ (prow & 7)) << 3) + (hi & 1) * 4;

    // exchange slots: (wid*2 + at)*256 + lane*4 floats, f32x4 per lane
    const int sxw = (wid * 2) * 256 + lane * 4;
    const int sxr = ((wid ^ 1) * 2) * 256 + lane * 4;

#define STAGE_K(IT, BUF)                                                            \
    {                                                                               \
        const u16* kb_ = Kb + (size_t)(key0 + (IT) * 64) * 512;                     \
        _Pragma("unroll") for (int r8_ = 0; r8_ < 8; ++r8_) {                       \
            int row_ = (wid << 3) + r8_;                                            \
            gload_lds16(kb_ + (size_t)row_ * 512 + ((lane ^ (row_ & 7)) << 3),      \
                        &lds_k[BUF][row_ * 512]);                                   \
        }                                                                           \
    }

// 16 reads, 32 MFMAs; each A-frag feeds 2 row-tiles; 4 indep chains (s00,s01,s10,s11)
#define S_COMPUTE(BUF)                                                              \
    {                                                                               \
        const u16* kb = &lds_k[BUF][0];                                             \
        const u16* p0e = kb + rowA + khofs + cbase;                                 \
        const u16* p0o = kb + rowA + khofs + (cbase ^ 32);                          \
        const u16* p1e = p0e + 16 * 512;                                            \
        const u16* p1o = p0o + 16 * 512;                                            \
        _Pragma("unroll") for (int kt2 = 0; kt2 < 4; ++kt2) {                       \
            bf16x8 a0e = *(const bf16x8*)(p0e + kt2 * 64);                          \
            bf16x8 a1e = *(const bf16x8*)(p1e + kt2 * 64);                          \
            bf16x8 a0o = *(const bf16x8*)(p0o + kt2 * 64);                          \
            bf16x8 a1o = *(const bf16x8*)(p1o + kt2 * 64);                          \
            s00 = MFMA16(a0e, qf[0][2 * kt2], s00);                                 \
            s10 = MFMA16(a0e, qf[1][2 * kt2], s10);                                 \
            s01 = MFMA16(a1e, qf[0][2 * kt2], s01);                                 \
            s11 = MFMA16(a1e, qf[1][2 * kt2], s11);                                 \
            s00 = MFMA16(a0o, qf[0][2 * kt2 + 1], s00);                             \
            s10 = MFMA16(a0o, qf[1][2 * kt2 + 1], s10);                             \
            s01 = MFMA16(a1o, qf[0][2 * kt2 + 1], s01);                             \
            s11 = MFMA16(a1o, qf[1][2 * kt2 + 1], s11);                             \
        }                                                                           \
    }

#define PV_STEP                                                                     \
    {                                                                               \
        _Pragma("unroll") for (int mt = 0; mt < 4; ++mt) {                          \
            int m = mt * 16 + lo;                                                   \
            int c0 = hi ^ (m & 7);                                                  \
            int c1 = (4 + hi) ^ (m & 7);                                            \
            bf16x8 pa0 = *(const bf16x8*)(&lds_p[m * 64 + c0 * 8]);                 \
            bf16x8 pa1 = *(const bf16x8*)(&lds_p[m * 64 + c1 * 8]);                 \
            _Pragma("unroll") for (int nt = 0; nt < 4; ++nt) {                      \
                f32x4 c_ = o[mt][nt];                                               \
                c_ = MFMA16(pa0, vb[nt][0], c_);                                    \
                c_ = MFMA16(pa1, vb[nt][1], c_);                                    \
                o[mt][nt] = c_;                                                     \
            }                                                                       \
        }                                                                           \
    }

#define VB_LOAD(T)                                                                  \
    {                                                                               \
        _Pragma("unroll") for (int nt = 0; nt < 4; ++nt) {                          \
            const u16* vrow = Vt + (size_t)(wid * 64 + nt * 16 + lo) * 8192 +       \
                              key0 + (T) * 64 + hi * 8;                             \
            vb[nt][0] = *(const bf16x8*)(vrow);                                     \
            vb[nt][1] = *(const bf16x8*)(vrow + 32);                                \
        }                                                                           \
    }

    // prologue
    STAGE_K(0, 0)
    asm volatile("s_waitcnt vmcnt(0)\n\ts_barrier" ::: "memory");

    for (int t = 0; t < 64; ++t) {
        const int cur = t & 1;
        VB_LOAD(t)
        asm volatile("" ::: "memory");  // vb(t) older than stage(t+1): FIFO counting
        if (t < 63) STAGE_K(t + 1, cur ^ 1)  // flies under S + exchange + PV

        // ---- S-partials: 32 rows x 32 keys over this wave's K-half ----
        f32x4 s00 = {0.f, 0.f, 0.f, 0.f}, s01 = s00, s10 = s00, s11 = s00;
        __builtin_amdgcn_s_setprio(1);
        S_COMPUTE(cur)
        __builtin_amdgcn_s_setprio(0);

        // write non-owned row-tile partials (rt = 1-kh) for the partner
        *(f32x4*)(&lds_sx[sxw]) = kh ? s00 : s10;
        *(f32x4*)(&lds_sx[sxw + 256]) = kh ? s01 : s11;
        asm volatile("s_waitcnt lgkmcnt(0)\n\ts_barrier" ::: "memory");  // sx visible

        // ---- combine with partner partials, exp, P-write for owned rows ----
        {
            f32x4 fA = (kh ? s10 : s00) + *(const f32x4*)(&lds_sx[sxr]);
            f32x4 fB = (kh ? s11 : s01) + *(const f32x4*)(&lds_sx[sxr + 256]);
            u16x4 w0, w1;
#pragma unroll
            for (int r = 0; r < 4; ++r) {
                float p0 = __expf(fA[r]);
                float p1 = __expf(fB[r]);
                lsum += p0 + p1;
                w0[r] = f2bf(p0);
                w1[r] = f2bf(p1);
            }
            *(u16x4*)(&lds_p[pw0]) = w0;
            *(u16x4*)(&lds_p[pw1]) = w1;
        }
        asm volatile("s_waitcnt lgkmcnt(0)\n\ts_barrier" ::: "memory");  // P visible

        // ---- PV(t): lds_p + vb(t) (compiler waits vb with counted vmcnt) ----
        __builtin_amdgcn_s_setprio(1);
        PV_STEP
        __builtin_amdgcn_s_setprio(0);

        // end barrier: stage(t+1) drained (flew under S+exch+PV); PV's lds_p reads done
        if (t < 63) asm volatile("s_waitcnt vmcnt(0)\n\ts_barrier" ::: "memory");
    }

    // ---- epilogue: lsum = owned 16 rows x this nj's 32 keys; reduce over hi ----
    lsum += __shfl_xor(lsum, 16);
    lsum += __shfl_xor(lsum, 32);
    if (lane < 16) s_l[nj][rs * 32 + kh * 16 + lo] = lsum;
    __syncthreads();

    const int lb = mtile * 2 + ks;  // logical partial index
    {
        float* Ob = Opart + (size_t)lb * (64 * 512);
#pragma unroll
        for (int mt = 0; mt < 4; ++mt)
#pragma unroll
            for (int nt = 0; nt < 4; ++nt)
#pragma unroll
                for (int r = 0; r < 4; ++r) {
                    int row = mt * 16 + hi * 4 + r;
                    int col = wid * 64 + nt * 16 + lo;
                    Ob[row * 512 + col] = o[mt][nt][r];
                }
        if (tid < 64) {
            lpart[lb * 64 + tid] = s_l[0][tid] + s_l[1][tid];
        }
    }
}

// ---------- combine the 2 key-split partials: out = (O0+O1)/(l0+l1) ----------
__global__ __launch_bounds__(256) void combine_kernel(const float* __restrict__ Opart,
                                                      const float* __restrict__ lpart,
                                                      float* __restrict__ out) {
    int i = blockIdx.x * 256 + threadIdx.x;  // float4 index; 8192*512/4 = 1048576 total
    int row = i >> 7;
    int c4 = i & 127;
    int mtile = row >> 6, rl = row & 63;
    int b0 = mtile * 2, b1 = b0 + 1;
    float inv = 1.0f / (lpart[b0 * 64 + rl] + lpart[b1 * 64 + rl]);
    f32x4 a = *(const f32x4*)(Opart + (size_t)b0 * 32768 + rl * 512 + c4 * 4);
    f32x4 b = *(const f32x4*)(Opart + (size_t)b1 * 32768 + rl * 512 + c4 * 4);
    f32x4 r = (a + b) * inv;
    *(f32x4*)(out + (size_t)row * 512 + c4 * 4) = r;
}

extern "C" void kernel_launch(void* const* d_in, const int* in_sizes, int n_in,
                              void* d_out, int out_size, void* d_ws, size_t ws_size,
                              hipStream_t stream) {
    const float* Q = (const float*)d_in[0];
    const float* K = (const float*)d_in[1];
    const float* V = (const float*)d_in[2];
    float* out = (float*)d_out;
    char* ws = (char*)d_ws;

    // ws layout (bytes): Qs 8M | Kb 8M | Vt 8M | Opart 32M | lpart 64K
    u16* Qs = (u16*)(ws + 0);
    u16* Kb = (u16*)(ws + 8388608);
    u16* Vt = (u16*)(ws + 16777216);
    float* Op = (float*)(ws + 25165824);
    float* lp = (float*)(ws + 58720256);

    const float scale = 0.08838834764831845f;  // 2 / sqrt(512): softmax(s)^2 renorm == softmax(2s)
    cvt_kernel<<<4096, 256, 0, stream>>>(Q, Qs, 1048576, scale);
    cvt_kernel<<<4096, 256, 0, stream>>>(K, Kb, 1048576, 1.0f);
    prep_vt<<<dim3(128, 8), 256, 0, stream>>>(V, Vt);
    flash_kernel<<<256, 512, 0, stream>>>(Qs, Kb, Vt, Op, lp);
    combine_kernel<<<4096, 256, 0, stream>>>(Op, lp, out);
}